// Round 9
// baseline (91.496 us; speedup 1.0000x reference)
//
#include <hip/hip_runtime.h>

// GATv2 layer, N=1024 nodes, C=256 channels. Flash-fused, dtype-adaptive.
// v6 = round-8 verified per-wave code, restructured to 8-wave (512-thread)
// blocks: 8 rows share one 32KB gt tile -> 4 blocks/CU x 8 waves = 8
// waves/SIMD target (VGPR 60 <= 64). Single-variable occupancy experiment.
//
// ws layout (bytes):
//   [0,   512K)    gsh  g_src as f16 [1024][256]
//   [512K, 1M)     gth  g_tgt as f16 [1024][256]
//   [1M,  1M+4K)   sgt06: 0.6 * dot(a, g_tgt[j]) per j, f32
//   [+,  +NS*1M)   po   partial O f32 [NS][1024][256]
//   next NS*4K     pm   partial max per (z,row)
//   next NS*4K     pls  partial denom per (z,row)

typedef unsigned short u16;
typedef unsigned int   u32;
typedef _Float16 h2 __attribute__((ext_vector_type(2)));

#define NNODE 1024
#define NC    256
#define NEG   0.2f

__device__ __forceinline__ float bf2f(u16 h) {
    u32 u = ((u32)h) << 16;
    return __builtin_bit_cast(float, u);
}
__device__ __forceinline__ u16 f2bf(float f) {
    u32 u = __builtin_bit_cast(u32, f);
    u32 r = (u + 0x7FFFu + ((u >> 16) & 1u)) >> 16;   // RNE
    return (u16)r;
}
__device__ __forceinline__ u16 f2h(float f) {
    _Float16 h = (_Float16)f;                         // RNE
    return __builtin_bit_cast(u16, h);
}
__device__ __forceinline__ h2 bch(u32 u) { return __builtin_bit_cast(h2, u); }
__device__ __forceinline__ h2 habs2(h2 y) {           // |y| packed: 1 v_and
    u32 u = __builtin_bit_cast(u32, y) & 0x7FFF7FFFu;
    return __builtin_bit_cast(h2, u);
}
__device__ __forceinline__ float dot2(h2 a, h2 b, float acc) {
#if __has_builtin(__builtin_amdgcn_fdot2)
    return __builtin_amdgcn_fdot2(a, b, acc, false);
#else
    acc = fmaf((float)a.x, (float)b.x, acc);
    return fmaf((float)a.y, (float)b.y, acc);
#endif
}

// per-wave dtype probe (uniform; verified rounds 2..8).
__device__ __forceinline__ int wave_detect(const u16* __restrict__ nodes, int lane)
{
    ushort4 v = *(const ushort4*)(nodes + lane * 4);
    const u16 h[4] = {v.x, v.y, v.z, v.w};
    int cnt = 0;
    #pragma unroll
    for (int q = 0; q < 4; ++q) {
        int e = (h[q] >> 7) & 0xFF;
        cnt += (e >= 132 || (e >= 1 && e <= 90)) ? 1 : 0;
    }
    #pragma unroll
    for (int off = 32; off; off >>= 1) cnt += __shfl_xor(cnt, off, 64);
    return (cnt >= 64) ? 0 : 1;
}

// LDS swizzle: 16B column-group XORed with row (verified rounds 7/8).
__device__ __forceinline__ int swz(int grp, int row) { return grp ^ (row & 31); }

// ---------------------------------------------------------------------------
// K1: g = nodes @ W^T + b, output packed f16 (gsh / gth). Verified body.
// grid (8, 32), 256 threads.
// ---------------------------------------------------------------------------
__global__ __launch_bounds__(256) void lin_kernel(
    const void* __restrict__ nodes_v,
    const void* __restrict__ Wsrc_v, const void* __restrict__ bsrc_v,
    const void* __restrict__ Wtgt_v, const void* __restrict__ btgt_v,
    u16* __restrict__ gsh, u16* __restrict__ gth)
{
    __shared__ float nT[64][34];   // [k][i]
    __shared__ float wT[64][68];   // [k][c]

    const int t  = threadIdx.x;
    const int bf = wave_detect((const u16*)nodes_v, t & 63);
    const int ct = blockIdx.x;
    const int it = blockIdx.y;
    const int i0 = it * 32;
    const bool is_src = (ct < 4);
    const int c0 = (is_src ? ct : ct - 4) * 64;
    const void* __restrict__ Wv = is_src ? Wsrc_v : Wtgt_v;
    const void* __restrict__ bv = is_src ? bsrc_v : btgt_v;
    u16* __restrict__ g         = is_src ? gsh : gth;

    const int tc = t & 15, ti = t >> 4;
    float acc[2][4] = {};

    for (int k0 = 0; k0 < NC; k0 += 64) {
        __syncthreads();
        {   // stage nodes tile [32 i][64 k] -> nT[k][i]
            int ii = t & 31, kg = t >> 5;
            float vals[8];
            if (bf) {
                uint4 v = *(const uint4*)((const u16*)nodes_v + (i0 + ii) * NC + k0 + kg * 8);
                const u16* pv = (const u16*)&v;
                #pragma unroll
                for (int q = 0; q < 8; ++q) vals[q] = bf2f(pv[q]);
            } else {
                const float* nf = (const float*)nodes_v;
                float4 v0 = *(const float4*)(nf + (i0 + ii) * NC + k0 + kg * 8);
                float4 v1 = *(const float4*)(nf + (i0 + ii) * NC + k0 + kg * 8 + 4);
                vals[0] = v0.x; vals[1] = v0.y; vals[2] = v0.z; vals[3] = v0.w;
                vals[4] = v1.x; vals[5] = v1.y; vals[6] = v1.z; vals[7] = v1.w;
            }
            #pragma unroll
            for (int q = 0; q < 8; ++q) nT[kg * 8 + q][ii] = vals[q];
        }
        {   // stage W tile [64 c][64 k] -> wT[k][c]
            int cc = t & 63, kg = t >> 6;
            float vals[16];
            if (bf) {
                const u16* W = (const u16*)Wv;
                uint4 v0 = *(const uint4*)(W + (c0 + cc) * NC + k0 + kg * 16);
                uint4 v1 = *(const uint4*)(W + (c0 + cc) * NC + k0 + kg * 16 + 8);
                const u16* p0 = (const u16*)&v0;
                const u16* p1 = (const u16*)&v1;
                #pragma unroll
                for (int q = 0; q < 8; ++q) { vals[q] = bf2f(p0[q]); vals[8 + q] = bf2f(p1[q]); }
            } else {
                const float* W = (const float*)Wv;
                #pragma unroll
                for (int h = 0; h < 4; ++h) {
                    float4 v = *(const float4*)(W + (c0 + cc) * NC + k0 + kg * 16 + 4 * h);
                    vals[4 * h + 0] = v.x; vals[4 * h + 1] = v.y;
                    vals[4 * h + 2] = v.z; vals[4 * h + 3] = v.w;
                }
            }
            #pragma unroll
            for (int q = 0; q < 16; ++q) wT[kg * 16 + q][cc] = vals[q];
        }
        __syncthreads();
        #pragma unroll 8
        for (int kk = 0; kk < 64; ++kk) {
            float2 av = *(const float2*)&nT[kk][2 * ti];
            float4 bvv = *(const float4*)&wT[kk][4 * tc];
            float sa[2] = {av.x, av.y};
            float tb[4] = {bvv.x, bvv.y, bvv.z, bvv.w};
            #pragma unroll
            for (int a = 0; a < 2; ++a)
                #pragma unroll
                for (int b = 0; b < 4; ++b)
                    acc[a][b] = fmaf(sa[a], tb[b], acc[a][b]);
        }
    }

    float bb[4];
    #pragma unroll
    for (int q = 0; q < 4; ++q)
        bb[q] = bf ? bf2f(((const u16*)bv)[c0 + 4 * tc + q])
                   : ((const float*)bv)[c0 + 4 * tc + q];
    #pragma unroll
    for (int a = 0; a < 2; ++a) {
        int irow = i0 + 2 * ti + a;
        ushort4 ov;
        ov.x = f2h(acc[a][0] + bb[0]);
        ov.y = f2h(acc[a][1] + bb[1]);
        ov.z = f2h(acc[a][2] + bb[2]);
        ov.w = f2h(acc[a][3] + bb[3]);
        *(ushort4*)(g + (size_t)irow * NC + c0 + 4 * tc) = ov;
    }
}

// ---------------------------------------------------------------------------
// K1b: sgt06[j] = 0.6 * sum_c a_c * g_tgt[j][c]  (verified round 8).
// grid 256 x 256; wave = row.
// ---------------------------------------------------------------------------
__global__ __launch_bounds__(256) void sdot_kernel(
    const u16* __restrict__ gth, const void* __restrict__ aw_v,
    const u16* __restrict__ nodes_u16, float* __restrict__ sgt06)
{
    const int t    = threadIdx.x;
    const int lane = t & 63;
    const int bf   = wave_detect(nodes_u16, lane);
    const int row  = blockIdx.x * 4 + (t >> 6);

    float a0, a1, a2, a3;
    if (bf) {
        ushort4 a4 = *(const ushort4*)((const u16*)aw_v + lane * 4);
        a0 = bf2f(a4.x); a1 = bf2f(a4.y); a2 = bf2f(a4.z); a3 = bf2f(a4.w);
    } else {
        float4 a4 = *(const float4*)((const float*)aw_v + lane * 4);
        a0 = a4.x; a1 = a4.y; a2 = a4.z; a3 = a4.w;
    }
    ushort4 gv = *(const ushort4*)(gth + (size_t)row * NC + lane * 4);
    float s = a0 * (float)__builtin_bit_cast(_Float16, gv.x)
            + a1 * (float)__builtin_bit_cast(_Float16, gv.y)
            + a2 * (float)__builtin_bit_cast(_Float16, gv.z)
            + a3 * (float)__builtin_bit_cast(_Float16, gv.w);
    #pragma unroll
    for (int off = 32; off; off >>= 1) s += __shfl_xor(s, off, 64);
    if (lane == 0) sgt06[row] = 0.6f * s;
}

// ---------------------------------------------------------------------------
// K2: fused score + online softmax + PV. 512 threads, 8 waves, 1 row/wave.
// Per-wave code identical to round 8 (verified); staging is 4 b128/thread.
// s = absdot + Sgs06 + sgt06[j]  (a32 holds 0.4*a).
// ---------------------------------------------------------------------------
__global__ __launch_bounds__(512, 8) void fused_kernel(
    const u16* __restrict__ gsh, const u16* __restrict__ gth,
    const void* __restrict__ aw_v, const int* __restrict__ adj,
    const u16* __restrict__ nodes_u16, const float* __restrict__ sgt06,
    int jcnt, float* __restrict__ po, float* __restrict__ pm,
    float* __restrict__ pls, void* __restrict__ out_v)
{
    __shared__ u32   gt32[64 * 128];  // swizzled, 32 KB
    __shared__ u32   a32[128];        // 0.4*a as f16x2
    __shared__ float p_lds[8][64];

    const int t    = threadIdx.x;
    const int i    = t >> 6;          // wave id = local row (0..7)
    const int lane = t & 63;
    const int bf   = wave_detect(nodes_u16, lane);
    const int row  = blockIdx.x * 8 + i;
    const int z    = blockIdx.y;
    const int jbase = z * jcnt;
    const int jl = lane & 15, q  = lane >> 4;   // score layout
    const int oc = lane & 31, hh = lane >> 5;   // PV layout

    if (t < 128) {                    // stage 0.4*a as f16x2 (flag-converted)
        float a0, a1;
        if (bf) { a0 = bf2f(((const u16*)aw_v)[2 * t]); a1 = bf2f(((const u16*)aw_v)[2 * t + 1]); }
        else    { a0 = ((const float*)aw_v)[2 * t];     a1 = ((const float*)aw_v)[2 * t + 1]; }
        h2 av; av.x = (_Float16)(0.4f * a0); av.y = (_Float16)(0.4f * a1);
        a32[t] = __builtin_bit_cast(u32, av);
    }

    // g_src quarter (64 ch) into registers: 32 x h2
    u32 gsr[32];
    {
        const u16* src = gsh + (size_t)row * NC + q * 64;
        #pragma unroll
        for (int k = 0; k < 8; ++k) {
            uint4 gv = *(const uint4*)(src + 8 * k);
            gsr[4 * k + 0] = gv.x; gsr[4 * k + 1] = gv.y;
            gsr[4 * k + 2] = gv.z; gsr[4 * k + 3] = gv.w;
        }
    }
    __syncthreads();                  // a32 visible

    // Sgs06 = 0.6 * dot(a, g_src[row]) = 1.5 * dot(0.4a, gsr), all lanes
    float Sgs06;
    {
        float sg = 0.f;
        #pragma unroll
        for (int k = 0; k < 8; ++k) {
            uint4 a4 = *(const uint4*)&a32[q * 32 + 4 * k];
            sg = dot2(bch(a4.x), bch(gsr[4 * k + 0]), sg);
            sg = dot2(bch(a4.y), bch(gsr[4 * k + 1]), sg);
            sg = dot2(bch(a4.z), bch(gsr[4 * k + 2]), sg);
            sg = dot2(bch(a4.w), bch(gsr[4 * k + 3]), sg);
        }
        sg += __shfl_xor(sg, 16, 64);
        sg += __shfl_xor(sg, 32, 64);
        Sgs06 = 1.5f * sg;
    }

    float m = -1e30f, l = 0.f;
    float of[8] = {};                 // ch 8*oc .. 8*oc+7 (j-parity hh)

    for (int j0 = jbase; j0 < jbase + jcnt; j0 += 64) {
        __syncthreads();              // prev tile's PV reads done
        {   // stage gt tile, swizzled: rr = t&63, kg = t>>6 covers 4 granules
            int rr = t & 63, kg = t >> 6;
            const u16* src = gth + (size_t)(j0 + rr) * NC + kg * 32;
            u32* dst = gt32 + rr * 128;
            #pragma unroll
            for (int c = 0; c < 4; ++c) {
                uint4 v = *(const uint4*)(src + 8 * c);
                *(uint4*)(dst + swz(kg * 4 + c, rr) * 4) = v;
            }
        }
        __syncthreads();

        const float sgtj = sgt06[j0 + lane];

        // ---- score abs-part: 4 passes x 16 j, 64-ch per-lane partial ----
        float spv[4] = {};
        #pragma unroll
        for (int k = 0; k < 8; ++k) {
            uint4 a4 = *(const uint4*)&a32[q * 32 + 4 * k];
            h2 a0 = bch(a4.x), a1 = bch(a4.y), a2 = bch(a4.z), a3 = bch(a4.w);
            h2 g0 = bch(gsr[4 * k + 0]), g1 = bch(gsr[4 * k + 1]),
               g2 = bch(gsr[4 * k + 2]), g3 = bch(gsr[4 * k + 3]);
            #pragma unroll
            for (int p = 0; p < 4; ++p) {
                const int rowp = 16 * p + jl;
                uint4 g4 = *(const uint4*)&gt32[rowp * 128 + swz(q * 8 + k, rowp) * 4];
                spv[p] = dot2(a0, habs2(g0 + bch(g4.x)), spv[p]);
                spv[p] = dot2(a1, habs2(g1 + bch(g4.y)), spv[p]);
                spv[p] = dot2(a2, habs2(g2 + bch(g4.z)), spv[p]);
                spv[p] = dot2(a3, habs2(g3 + bch(g4.w)), spv[p]);
            }
        }
        #pragma unroll
        for (int p = 0; p < 4; ++p) {   // reduce over q (lane bits 4,5)
            spv[p] += __shfl_xor(spv[p], 16, 64);
            spv[p] += __shfl_xor(spv[p], 32, 64);
        }
        // j = j0 + lane: abs-part in spv[lane>>4]; add linear terms
        const float sabs = (lane < 16) ? spv[0] : (lane < 32) ? spv[1]
                         : (lane < 48) ? spv[2] : spv[3];
        const float s = sabs + Sgs06 + sgtj;

        // ---- online softmax (verified block), wave = row ----
        const int valid = adj[(size_t)row * NNODE + j0 + lane];
        float sm = valid ? s : -1e30f;
        float tmax = sm;
        #pragma unroll
        for (int off = 32; off; off >>= 1)
            tmax = fmaxf(tmax, __shfl_xor(tmax, off, 64));
        const float mn    = fmaxf(m, tmax);
        const float alpha = __expf(m - mn);
        const float p     = valid ? __expf(s - mn) : 0.f;
        float ps = p;
        #pragma unroll
        for (int off = 32; off; off >>= 1) ps += __shfl_xor(ps, off, 64);
        l = l * alpha + ps;
        m = mn;
        p_lds[i][lane] = p;           // wave-local producer/consumer

        // ---- PV: per 2 j one b128 (8 ch) + one p broadcast ----
        #pragma unroll
        for (int k = 0; k < 8; ++k) of[k] *= alpha;
        #pragma unroll 8
        for (int jp = 0; jp < 32; ++jp) {
            const int j = 2 * jp + hh;
            const float w = p_lds[i][j];
            uint4 g4 = *(const uint4*)&gt32[j * 128 + swz(oc, j) * 4];
            h2 v0 = bch(g4.x), v1 = bch(g4.y), v2 = bch(g4.z), v3 = bch(g4.w);
            of[0] = fmaf(w, (float)v0.x, of[0]);
            of[1] = fmaf(w, (float)v0.y, of[1]);
            of[2] = fmaf(w, (float)v1.x, of[2]);
            of[3] = fmaf(w, (float)v1.y, of[3]);
            of[4] = fmaf(w, (float)v2.x, of[4]);
            of[5] = fmaf(w, (float)v2.y, of[5]);
            of[6] = fmaf(w, (float)v3.x, of[6]);
            of[7] = fmaf(w, (float)v3.y, of[7]);
        }
    }

    // combine the two j-parity halves; lanes 0..31 hold full sums
    #pragma unroll
    for (int k = 0; k < 8; ++k) of[k] += __shfl_xor(of[k], 32, 64);

    if (lane < 32) {
        if (out_v) {                  // NS == 1 direct path
            const float inv = 1.0f / l;   // self-loop -> l > 0
            if (bf) {
                u16* out = (u16*)out_v;
                ushort4 oa, ob;
                oa.x = f2bf(of[0] * inv); oa.y = f2bf(of[1] * inv);
                oa.z = f2bf(of[2] * inv); oa.w = f2bf(of[3] * inv);
                ob.x = f2bf(of[4] * inv); ob.y = f2bf(of[5] * inv);
                ob.z = f2bf(of[6] * inv); ob.w = f2bf(of[7] * inv);
                *(ushort4*)(out + (size_t)row * NC + 8 * oc)     = oa;
                *(ushort4*)(out + (size_t)row * NC + 8 * oc + 4) = ob;
            } else {
                float* out = (float*)out_v;
                *(float4*)(out + (size_t)row * NC + 8 * oc) =
                    make_float4(of[0] * inv, of[1] * inv, of[2] * inv, of[3] * inv);
                *(float4*)(out + (size_t)row * NC + 8 * oc + 4) =
                    make_float4(of[4] * inv, of[5] * inv, of[6] * inv, of[7] * inv);
            }
        } else {                      // partial path
            float* pp = po + ((size_t)z * NNODE + row) * NC + 8 * oc;
            *(float4*)pp       = make_float4(of[0], of[1], of[2], of[3]);
            *(float4*)(pp + 4) = make_float4(of[4], of[5], of[6], of[7]);
        }
    }
    if (!out_v && lane == 0) {
        pm [(size_t)z * NNODE + row] = m;
        pls[(size_t)z * NNODE + row] = l;
    }
}

// ---------------------------------------------------------------------------
// K3: merge NS partials per row (verified body). Empty chunks contribute 0.
// ---------------------------------------------------------------------------
__global__ __launch_bounds__(256) void combine_kernel(
    const float* __restrict__ po, const float* __restrict__ pm,
    const float* __restrict__ pls, const u16* __restrict__ nodes_u16,
    int ns, void* __restrict__ out_v)
{
    const int bf  = wave_detect(nodes_u16, threadIdx.x & 63);
    const int row = blockIdx.x;
    const int c   = threadIdx.x;

    float mstar = -1e30f;
    for (int zz = 0; zz < ns; ++zz)
        mstar = fmaxf(mstar, pm[zz * NNODE + row]);

    float acc = 0.f, lsum = 0.f;
    for (int zz = 0; zz < ns; ++zz) {
        const float wz = __expf(pm[zz * NNODE + row] - mstar);
        lsum = fmaf(pls[zz * NNODE + row], wz, lsum);
        acc  = fmaf(po[(size_t)(zz * NNODE + row) * NC + c], wz, acc);
    }
    const float v = acc / lsum;
    if (bf) ((u16*)out_v)[row * NC + c] = f2bf(v);
    else    ((float*)out_v)[row * NC + c] = v;
}

extern "C" void kernel_launch(void* const* d_in, const int* in_sizes, int n_in,
                              void* d_out, int out_size, void* d_ws, size_t ws_size,
                              hipStream_t stream)
{
    const u16* nodes_u16 = (const u16*)d_in[0];
    const int* adj       = (const int*)d_in[1];

    char*  wsb   = (char*)d_ws;
    u16*   gsh   = (u16*)wsb;
    u16*   gth   = gsh + (size_t)NNODE * NC;
    float* sgt06 = (float*)(wsb + 2ull * NNODE * NC * sizeof(u16));

    lin_kernel<<<dim3(8, 32), 256, 0, stream>>>(d_in[0], d_in[2], d_in[3],
                                                d_in[4], d_in[5], gsh, gth);
    sdot_kernel<<<256, 256, 0, stream>>>(gth, d_in[6], nodes_u16, sgt06);

    const size_t base = 2ull * NNODE * NC * sizeof(u16) + NNODE * sizeof(float);
    const size_t per  = 4ull * NNODE * NC + 8ull * NNODE;  // bytes per NS unit
    int NS = 0;
    if      (ws_size >= base + 8 * per) NS = 8;
    else if (ws_size >= base + 4 * per) NS = 4;
    else if (ws_size >= base + 2 * per) NS = 2;

    if (NS) {
        float* po  = (float*)(wsb + base);
        float* pm  = po + (size_t)NS * NNODE * NC;
        float* pls = pm + (size_t)NS * NNODE;
        fused_kernel<<<dim3(128, NS), 512, 0, stream>>>(
            gsh, gth, d_in[6], adj, nodes_u16, sgt06, NNODE / NS,
            po, pm, pls, nullptr);
        combine_kernel<<<NNODE, 256, 0, stream>>>(po, pm, pls, nodes_u16, NS, d_out);
    } else {
        fused_kernel<<<dim3(128, 1), 512, 0, stream>>>(
            gsh, gth, d_in[6], adj, nodes_u16, sgt06, NNODE,
            nullptr, nullptr, nullptr, d_out);
    }
}

// Round 10
// 66.532 us; speedup vs baseline: 1.3752x; 1.3752x over previous
//
#include <hip/hip_runtime.h>

// GATv2 layer, N=1024 nodes, C=256 channels. Flash-fused, dtype-adaptive.
// v7 = round-9 structure (8-wave 512-thread blocks, one shared 32KB gt tile)
// with the launch-bounds arithmetic FIXED: for B=512, w waves/SIMD needs
// arg = w*4/(B/64); w=8 -> arg=4 (round 9's arg=8 meant w=16 -> VGPR cap 32
// -> catastrophic spill). __launch_bounds__(512,4) => VGPR cap 64 >= 60 used.
//
// ws layout (bytes):
//   [0,   512K)    gsh  g_src as f16 [1024][256]
//   [512K, 1M)     gth  g_tgt as f16 [1024][256]
//   [1M,  1M+4K)   sgt06: 0.6 * dot(a, g_tgt[j]) per j, f32
//   [+,  +NS*1M)   po   partial O f32 [NS][1024][256]
//   next NS*4K     pm   partial max per (z,row)
//   next NS*4K     pls  partial denom per (z,row)

typedef unsigned short u16;
typedef unsigned int   u32;
typedef _Float16 h2 __attribute__((ext_vector_type(2)));

#define NNODE 1024
#define NC    256
#define NEG   0.2f

__device__ __forceinline__ float bf2f(u16 h) {
    u32 u = ((u32)h) << 16;
    return __builtin_bit_cast(float, u);
}
__device__ __forceinline__ u16 f2bf(float f) {
    u32 u = __builtin_bit_cast(u32, f);
    u32 r = (u + 0x7FFFu + ((u >> 16) & 1u)) >> 16;   // RNE
    return (u16)r;
}
__device__ __forceinline__ u16 f2h(float f) {
    _Float16 h = (_Float16)f;                         // RNE
    return __builtin_bit_cast(u16, h);
}
__device__ __forceinline__ h2 bch(u32 u) { return __builtin_bit_cast(h2, u); }
__device__ __forceinline__ h2 habs2(h2 y) {           // |y| packed: 1 v_and
    u32 u = __builtin_bit_cast(u32, y) & 0x7FFF7FFFu;
    return __builtin_bit_cast(h2, u);
}
__device__ __forceinline__ float dot2(h2 a, h2 b, float acc) {
#if __has_builtin(__builtin_amdgcn_fdot2)
    return __builtin_amdgcn_fdot2(a, b, acc, false);
#else
    acc = fmaf((float)a.x, (float)b.x, acc);
    return fmaf((float)a.y, (float)b.y, acc);
#endif
}

// per-wave dtype probe (uniform; verified rounds 2..9).
__device__ __forceinline__ int wave_detect(const u16* __restrict__ nodes, int lane)
{
    ushort4 v = *(const ushort4*)(nodes + lane * 4);
    const u16 h[4] = {v.x, v.y, v.z, v.w};
    int cnt = 0;
    #pragma unroll
    for (int q = 0; q < 4; ++q) {
        int e = (h[q] >> 7) & 0xFF;
        cnt += (e >= 132 || (e >= 1 && e <= 90)) ? 1 : 0;
    }
    #pragma unroll
    for (int off = 32; off; off >>= 1) cnt += __shfl_xor(cnt, off, 64);
    return (cnt >= 64) ? 0 : 1;
}

// LDS swizzle: 16B column-group XORed with row (verified rounds 7/8).
__device__ __forceinline__ int swz(int grp, int row) { return grp ^ (row & 31); }

// ---------------------------------------------------------------------------
// K1: g = nodes @ W^T + b, output packed f16 (gsh / gth). Verified body.
// grid (8, 32), 256 threads.
// ---------------------------------------------------------------------------
__global__ __launch_bounds__(256) void lin_kernel(
    const void* __restrict__ nodes_v,
    const void* __restrict__ Wsrc_v, const void* __restrict__ bsrc_v,
    const void* __restrict__ Wtgt_v, const void* __restrict__ btgt_v,
    u16* __restrict__ gsh, u16* __restrict__ gth)
{
    __shared__ float nT[64][34];   // [k][i]
    __shared__ float wT[64][68];   // [k][c]

    const int t  = threadIdx.x;
    const int bf = wave_detect((const u16*)nodes_v, t & 63);
    const int ct = blockIdx.x;
    const int it = blockIdx.y;
    const int i0 = it * 32;
    const bool is_src = (ct < 4);
    const int c0 = (is_src ? ct : ct - 4) * 64;
    const void* __restrict__ Wv = is_src ? Wsrc_v : Wtgt_v;
    const void* __restrict__ bv = is_src ? bsrc_v : btgt_v;
    u16* __restrict__ g         = is_src ? gsh : gth;

    const int tc = t & 15, ti = t >> 4;
    float acc[2][4] = {};

    for (int k0 = 0; k0 < NC; k0 += 64) {
        __syncthreads();
        {   // stage nodes tile [32 i][64 k] -> nT[k][i]
            int ii = t & 31, kg = t >> 5;
            float vals[8];
            if (bf) {
                uint4 v = *(const uint4*)((const u16*)nodes_v + (i0 + ii) * NC + k0 + kg * 8);
                const u16* pv = (const u16*)&v;
                #pragma unroll
                for (int q = 0; q < 8; ++q) vals[q] = bf2f(pv[q]);
            } else {
                const float* nf = (const float*)nodes_v;
                float4 v0 = *(const float4*)(nf + (i0 + ii) * NC + k0 + kg * 8);
                float4 v1 = *(const float4*)(nf + (i0 + ii) * NC + k0 + kg * 8 + 4);
                vals[0] = v0.x; vals[1] = v0.y; vals[2] = v0.z; vals[3] = v0.w;
                vals[4] = v1.x; vals[5] = v1.y; vals[6] = v1.z; vals[7] = v1.w;
            }
            #pragma unroll
            for (int q = 0; q < 8; ++q) nT[kg * 8 + q][ii] = vals[q];
        }
        {   // stage W tile [64 c][64 k] -> wT[k][c]
            int cc = t & 63, kg = t >> 6;
            float vals[16];
            if (bf) {
                const u16* W = (const u16*)Wv;
                uint4 v0 = *(const uint4*)(W + (c0 + cc) * NC + k0 + kg * 16);
                uint4 v1 = *(const uint4*)(W + (c0 + cc) * NC + k0 + kg * 16 + 8);
                const u16* p0 = (const u16*)&v0;
                const u16* p1 = (const u16*)&v1;
                #pragma unroll
                for (int q = 0; q < 8; ++q) { vals[q] = bf2f(p0[q]); vals[8 + q] = bf2f(p1[q]); }
            } else {
                const float* W = (const float*)Wv;
                #pragma unroll
                for (int h = 0; h < 4; ++h) {
                    float4 v = *(const float4*)(W + (c0 + cc) * NC + k0 + kg * 16 + 4 * h);
                    vals[4 * h + 0] = v.x; vals[4 * h + 1] = v.y;
                    vals[4 * h + 2] = v.z; vals[4 * h + 3] = v.w;
                }
            }
            #pragma unroll
            for (int q = 0; q < 16; ++q) wT[kg * 16 + q][cc] = vals[q];
        }
        __syncthreads();
        #pragma unroll 8
        for (int kk = 0; kk < 64; ++kk) {
            float2 av = *(const float2*)&nT[kk][2 * ti];
            float4 bvv = *(const float4*)&wT[kk][4 * tc];
            float sa[2] = {av.x, av.y};
            float tb[4] = {bvv.x, bvv.y, bvv.z, bvv.w};
            #pragma unroll
            for (int a = 0; a < 2; ++a)
                #pragma unroll
                for (int b = 0; b < 4; ++b)
                    acc[a][b] = fmaf(sa[a], tb[b], acc[a][b]);
        }
    }

    float bb[4];
    #pragma unroll
    for (int q = 0; q < 4; ++q)
        bb[q] = bf ? bf2f(((const u16*)bv)[c0 + 4 * tc + q])
                   : ((const float*)bv)[c0 + 4 * tc + q];
    #pragma unroll
    for (int a = 0; a < 2; ++a) {
        int irow = i0 + 2 * ti + a;
        ushort4 ov;
        ov.x = f2h(acc[a][0] + bb[0]);
        ov.y = f2h(acc[a][1] + bb[1]);
        ov.z = f2h(acc[a][2] + bb[2]);
        ov.w = f2h(acc[a][3] + bb[3]);
        *(ushort4*)(g + (size_t)irow * NC + c0 + 4 * tc) = ov;
    }
}

// ---------------------------------------------------------------------------
// K1b: sgt06[j] = 0.6 * sum_c a_c * g_tgt[j][c]  (verified round 8).
// grid 256 x 256; wave = row.
// ---------------------------------------------------------------------------
__global__ __launch_bounds__(256) void sdot_kernel(
    const u16* __restrict__ gth, const void* __restrict__ aw_v,
    const u16* __restrict__ nodes_u16, float* __restrict__ sgt06)
{
    const int t    = threadIdx.x;
    const int lane = t & 63;
    const int bf   = wave_detect(nodes_u16, lane);
    const int row  = blockIdx.x * 4 + (t >> 6);

    float a0, a1, a2, a3;
    if (bf) {
        ushort4 a4 = *(const ushort4*)((const u16*)aw_v + lane * 4);
        a0 = bf2f(a4.x); a1 = bf2f(a4.y); a2 = bf2f(a4.z); a3 = bf2f(a4.w);
    } else {
        float4 a4 = *(const float4*)((const float*)aw_v + lane * 4);
        a0 = a4.x; a1 = a4.y; a2 = a4.z; a3 = a4.w;
    }
    ushort4 gv = *(const ushort4*)(gth + (size_t)row * NC + lane * 4);
    float s = a0 * (float)__builtin_bit_cast(_Float16, gv.x)
            + a1 * (float)__builtin_bit_cast(_Float16, gv.y)
            + a2 * (float)__builtin_bit_cast(_Float16, gv.z)
            + a3 * (float)__builtin_bit_cast(_Float16, gv.w);
    #pragma unroll
    for (int off = 32; off; off >>= 1) s += __shfl_xor(s, off, 64);
    if (lane == 0) sgt06[row] = 0.6f * s;
}

// ---------------------------------------------------------------------------
// K2: fused score + online softmax + PV. 512 threads, 8 waves, 1 row/wave.
// Per-wave code identical to round 8 (verified). launch_bounds(512,4):
// arg = w*4/(B/64) with w=8 waves/SIMD -> VGPR cap 64 (kernel uses ~60).
// ---------------------------------------------------------------------------
__global__ __launch_bounds__(512, 4) void fused_kernel(
    const u16* __restrict__ gsh, const u16* __restrict__ gth,
    const void* __restrict__ aw_v, const int* __restrict__ adj,
    const u16* __restrict__ nodes_u16, const float* __restrict__ sgt06,
    int jcnt, float* __restrict__ po, float* __restrict__ pm,
    float* __restrict__ pls, void* __restrict__ out_v)
{
    __shared__ u32   gt32[64 * 128];  // swizzled, 32 KB
    __shared__ u32   a32[128];        // 0.4*a as f16x2
    __shared__ float p_lds[8][64];

    const int t    = threadIdx.x;
    const int i    = t >> 6;          // wave id = local row (0..7)
    const int lane = t & 63;
    const int bf   = wave_detect(nodes_u16, lane);
    const int row  = blockIdx.x * 8 + i;
    const int z    = blockIdx.y;
    const int jbase = z * jcnt;
    const int jl = lane & 15, q  = lane >> 4;   // score layout
    const int oc = lane & 31, hh = lane >> 5;   // PV layout

    if (t < 128) {                    // stage 0.4*a as f16x2 (flag-converted)
        float a0, a1;
        if (bf) { a0 = bf2f(((const u16*)aw_v)[2 * t]); a1 = bf2f(((const u16*)aw_v)[2 * t + 1]); }
        else    { a0 = ((const float*)aw_v)[2 * t];     a1 = ((const float*)aw_v)[2 * t + 1]; }
        h2 av; av.x = (_Float16)(0.4f * a0); av.y = (_Float16)(0.4f * a1);
        a32[t] = __builtin_bit_cast(u32, av);
    }

    // g_src quarter (64 ch) into registers: 32 x h2
    u32 gsr[32];
    {
        const u16* src = gsh + (size_t)row * NC + q * 64;
        #pragma unroll
        for (int k = 0; k < 8; ++k) {
            uint4 gv = *(const uint4*)(src + 8 * k);
            gsr[4 * k + 0] = gv.x; gsr[4 * k + 1] = gv.y;
            gsr[4 * k + 2] = gv.z; gsr[4 * k + 3] = gv.w;
        }
    }
    __syncthreads();                  // a32 visible

    // Sgs06 = 0.6 * dot(a, g_src[row]) = 1.5 * dot(0.4a, gsr), all lanes
    float Sgs06;
    {
        float sg = 0.f;
        #pragma unroll
        for (int k = 0; k < 8; ++k) {
            uint4 a4 = *(const uint4*)&a32[q * 32 + 4 * k];
            sg = dot2(bch(a4.x), bch(gsr[4 * k + 0]), sg);
            sg = dot2(bch(a4.y), bch(gsr[4 * k + 1]), sg);
            sg = dot2(bch(a4.z), bch(gsr[4 * k + 2]), sg);
            sg = dot2(bch(a4.w), bch(gsr[4 * k + 3]), sg);
        }
        sg += __shfl_xor(sg, 16, 64);
        sg += __shfl_xor(sg, 32, 64);
        Sgs06 = 1.5f * sg;
    }

    float m = -1e30f, l = 0.f;
    float of[8] = {};                 // ch 8*oc .. 8*oc+7 (j-parity hh)

    for (int j0 = jbase; j0 < jbase + jcnt; j0 += 64) {
        __syncthreads();              // prev tile's PV reads done
        {   // stage gt tile, swizzled: rr = t&63, kg = t>>6 covers 4 granules
            int rr = t & 63, kg = t >> 6;
            const u16* src = gth + (size_t)(j0 + rr) * NC + kg * 32;
            u32* dst = gt32 + rr * 128;
            #pragma unroll
            for (int c = 0; c < 4; ++c) {
                uint4 v = *(const uint4*)(src + 8 * c);
                *(uint4*)(dst + swz(kg * 4 + c, rr) * 4) = v;
            }
        }
        __syncthreads();

        const float sgtj = sgt06[j0 + lane];

        // ---- score abs-part: 4 passes x 16 j, 64-ch per-lane partial ----
        float spv[4] = {};
        #pragma unroll
        for (int k = 0; k < 8; ++k) {
            uint4 a4 = *(const uint4*)&a32[q * 32 + 4 * k];
            h2 a0 = bch(a4.x), a1 = bch(a4.y), a2 = bch(a4.z), a3 = bch(a4.w);
            h2 g0 = bch(gsr[4 * k + 0]), g1 = bch(gsr[4 * k + 1]),
               g2 = bch(gsr[4 * k + 2]), g3 = bch(gsr[4 * k + 3]);
            #pragma unroll
            for (int p = 0; p < 4; ++p) {
                const int rowp = 16 * p + jl;
                uint4 g4 = *(const uint4*)&gt32[rowp * 128 + swz(q * 8 + k, rowp) * 4];
                spv[p] = dot2(a0, habs2(g0 + bch(g4.x)), spv[p]);
                spv[p] = dot2(a1, habs2(g1 + bch(g4.y)), spv[p]);
                spv[p] = dot2(a2, habs2(g2 + bch(g4.z)), spv[p]);
                spv[p] = dot2(a3, habs2(g3 + bch(g4.w)), spv[p]);
            }
        }
        #pragma unroll
        for (int p = 0; p < 4; ++p) {   // reduce over q (lane bits 4,5)
            spv[p] += __shfl_xor(spv[p], 16, 64);
            spv[p] += __shfl_xor(spv[p], 32, 64);
        }
        // j = j0 + lane: abs-part in spv[lane>>4]; add linear terms
        const float sabs = (lane < 16) ? spv[0] : (lane < 32) ? spv[1]
                         : (lane < 48) ? spv[2] : spv[3];
        const float s = sabs + Sgs06 + sgtj;

        // ---- online softmax (verified block), wave = row ----
        const int valid = adj[(size_t)row * NNODE + j0 + lane];
        float sm = valid ? s : -1e30f;
        float tmax = sm;
        #pragma unroll
        for (int off = 32; off; off >>= 1)
            tmax = fmaxf(tmax, __shfl_xor(tmax, off, 64));
        const float mn    = fmaxf(m, tmax);
        const float alpha = __expf(m - mn);
        const float p     = valid ? __expf(s - mn) : 0.f;
        float ps = p;
        #pragma unroll
        for (int off = 32; off; off >>= 1) ps += __shfl_xor(ps, off, 64);
        l = l * alpha + ps;
        m = mn;
        p_lds[i][lane] = p;           // wave-local producer/consumer

        // ---- PV: per 2 j one b128 (8 ch) + one p broadcast ----
        #pragma unroll
        for (int k = 0; k < 8; ++k) of[k] *= alpha;
        #pragma unroll 8
        for (int jp = 0; jp < 32; ++jp) {
            const int j = 2 * jp + hh;
            const float w = p_lds[i][j];
            uint4 g4 = *(const uint4*)&gt32[j * 128 + swz(oc, j) * 4];
            h2 v0 = bch(g4.x), v1 = bch(g4.y), v2 = bch(g4.z), v3 = bch(g4.w);
            of[0] = fmaf(w, (float)v0.x, of[0]);
            of[1] = fmaf(w, (float)v0.y, of[1]);
            of[2] = fmaf(w, (float)v1.x, of[2]);
            of[3] = fmaf(w, (float)v1.y, of[3]);
            of[4] = fmaf(w, (float)v2.x, of[4]);
            of[5] = fmaf(w, (float)v2.y, of[5]);
            of[6] = fmaf(w, (float)v3.x, of[6]);
            of[7] = fmaf(w, (float)v3.y, of[7]);
        }
    }

    // combine the two j-parity halves; lanes 0..31 hold full sums
    #pragma unroll
    for (int k = 0; k < 8; ++k) of[k] += __shfl_xor(of[k], 32, 64);

    if (lane < 32) {
        if (out_v) {                  // NS == 1 direct path
            const float inv = 1.0f / l;   // self-loop -> l > 0
            if (bf) {
                u16* out = (u16*)out_v;
                ushort4 oa, ob;
                oa.x = f2bf(of[0] * inv); oa.y = f2bf(of[1] * inv);
                oa.z = f2bf(of[2] * inv); oa.w = f2bf(of[3] * inv);
                ob.x = f2bf(of[4] * inv); ob.y = f2bf(of[5] * inv);
                ob.z = f2bf(of[6] * inv); ob.w = f2bf(of[7] * inv);
                *(ushort4*)(out + (size_t)row * NC + 8 * oc)     = oa;
                *(ushort4*)(out + (size_t)row * NC + 8 * oc + 4) = ob;
            } else {
                float* out = (float*)out_v;
                *(float4*)(out + (size_t)row * NC + 8 * oc) =
                    make_float4(of[0] * inv, of[1] * inv, of[2] * inv, of[3] * inv);
                *(float4*)(out + (size_t)row * NC + 8 * oc + 4) =
                    make_float4(of[4] * inv, of[5] * inv, of[6] * inv, of[7] * inv);
            }
        } else {                      // partial path
            float* pp = po + ((size_t)z * NNODE + row) * NC + 8 * oc;
            *(float4*)pp       = make_float4(of[0], of[1], of[2], of[3]);
            *(float4*)(pp + 4) = make_float4(of[4], of[5], of[6], of[7]);
        }
    }
    if (!out_v && lane == 0) {
        pm [(size_t)z * NNODE + row] = m;
        pls[(size_t)z * NNODE + row] = l;
    }
}

// ---------------------------------------------------------------------------
// K3: merge NS partials per row (verified body). Empty chunks contribute 0.
// ---------------------------------------------------------------------------
__global__ __launch_bounds__(256) void combine_kernel(
    const float* __restrict__ po, const float* __restrict__ pm,
    const float* __restrict__ pls, const u16* __restrict__ nodes_u16,
    int ns, void* __restrict__ out_v)
{
    const int bf  = wave_detect(nodes_u16, threadIdx.x & 63);
    const int row = blockIdx.x;
    const int c   = threadIdx.x;

    float mstar = -1e30f;
    for (int zz = 0; zz < ns; ++zz)
        mstar = fmaxf(mstar, pm[zz * NNODE + row]);

    float acc = 0.f, lsum = 0.f;
    for (int zz = 0; zz < ns; ++zz) {
        const float wz = __expf(pm[zz * NNODE + row] - mstar);
        lsum = fmaf(pls[zz * NNODE + row], wz, lsum);
        acc  = fmaf(po[(size_t)(zz * NNODE + row) * NC + c], wz, acc);
    }
    const float v = acc / lsum;
    if (bf) ((u16*)out_v)[row * NC + c] = f2bf(v);
    else    ((float*)out_v)[row * NC + c] = v;
}

extern "C" void kernel_launch(void* const* d_in, const int* in_sizes, int n_in,
                              void* d_out, int out_size, void* d_ws, size_t ws_size,
                              hipStream_t stream)
{
    const u16* nodes_u16 = (const u16*)d_in[0];
    const int* adj       = (const int*)d_in[1];

    char*  wsb   = (char*)d_ws;
    u16*   gsh   = (u16*)wsb;
    u16*   gth   = gsh + (size_t)NNODE * NC;
    float* sgt06 = (float*)(wsb + 2ull * NNODE * NC * sizeof(u16));

    lin_kernel<<<dim3(8, 32), 256, 0, stream>>>(d_in[0], d_in[2], d_in[3],
                                                d_in[4], d_in[5], gsh, gth);
    sdot_kernel<<<256, 256, 0, stream>>>(gth, d_in[6], nodes_u16, sgt06);

    const size_t base = 2ull * NNODE * NC * sizeof(u16) + NNODE * sizeof(float);
    const size_t per  = 4ull * NNODE * NC + 8ull * NNODE;  // bytes per NS unit
    int NS = 0;
    if      (ws_size >= base + 8 * per) NS = 8;
    else if (ws_size >= base + 4 * per) NS = 4;
    else if (ws_size >= base + 2 * per) NS = 2;

    if (NS) {
        float* po  = (float*)(wsb + base);
        float* pm  = po + (size_t)NS * NNODE * NC;
        float* pls = pm + (size_t)NS * NNODE;
        fused_kernel<<<dim3(128, NS), 512, 0, stream>>>(
            gsh, gth, d_in[6], adj, nodes_u16, sgt06, NNODE / NS,
            po, pm, pls, nullptr);
        combine_kernel<<<NNODE, 256, 0, stream>>>(po, pm, pls, nodes_u16, NS, d_out);
    } else {
        fused_kernel<<<dim3(128, 1), 512, 0, stream>>>(
            gsh, gth, d_in[6], adj, nodes_u16, sgt06, NNODE,
            nullptr, nullptr, nullptr, d_out);
    }
}